// Round 1
// baseline (341.999 us; speedup 1.0000x reference)
//
#include <hip/hip_runtime.h>
#include <math.h>

#define B_SZ 1024
#define D_SZ 1024
#define L_SZ 512
#define E_SZ 16
#define NEG_SLOPE 0.2f

// ---------------------------------------------------------------------------
// Kernel 1: pooled[b,d] = mean(x[b,d,:]) + max(x[b,d,:])
// One 64-lane wave per row of 512 contiguous floats.
// Each lane: 2x float4 (8 floats). Coalesced: per pass, 64 lanes * 16B = 1KiB.
// ---------------------------------------------------------------------------
__global__ __launch_bounds__(256) void pool_kernel(const float* __restrict__ x,
                                                   float* __restrict__ pooled,
                                                   int nrows) {
    const int gtid = blockIdx.x * blockDim.x + threadIdx.x;
    const int row  = gtid >> 6;          // global wave index
    const int lane = threadIdx.x & 63;
    if (row >= nrows) return;

    const float4* xr = reinterpret_cast<const float4*>(x + (size_t)row * L_SZ);

    float s  = 0.0f;
    float mx = -INFINITY;
#pragma unroll
    for (int pass = 0; pass < 2; ++pass) {
        float4 v = xr[pass * 64 + lane];
        s += (v.x + v.y) + (v.z + v.w);
        mx = fmaxf(mx, fmaxf(fmaxf(v.x, v.y), fmaxf(v.z, v.w)));
    }

    // wave64 butterfly reduce
#pragma unroll
    for (int off = 32; off > 0; off >>= 1) {
        s  += __shfl_xor(s, off);
        mx  = fmaxf(mx, __shfl_xor(mx, off));
    }

    if (lane == 0) {
        pooled[row] = s * (1.0f / (float)L_SZ) + mx;
    }
}

// ---------------------------------------------------------------------------
// Kernel 2: per batch-row b:
//   logits[e] = leakyrelu( dot(pooled[b,:], W[e,:]) + bias[e] )
//   top-2 -> mask, softmax over masked -> gating
// One 256-thread block per row. Outputs: out[0 : B*E] = gating,
// out[B*E : 2*B*E] = mask.
// ---------------------------------------------------------------------------
__global__ __launch_bounds__(256) void gate_kernel(const float* __restrict__ pooled,
                                                   const float* __restrict__ W,
                                                   const float* __restrict__ bias,
                                                   float* __restrict__ out) {
    const int b = blockIdx.x;
    const int t = threadIdx.x;

    float acc[E_SZ];
#pragma unroll
    for (int e = 0; e < E_SZ; ++e) acc[e] = 0.0f;

    const float* prow = pooled + (size_t)b * D_SZ;
    for (int d = t; d < D_SZ; d += 256) {
        float p = prow[d];
#pragma unroll
        for (int e = 0; e < E_SZ; ++e) acc[e] += p * W[e * D_SZ + d];
    }

    // wave reduce each expert partial
#pragma unroll
    for (int e = 0; e < E_SZ; ++e) {
#pragma unroll
        for (int off = 32; off > 0; off >>= 1) acc[e] += __shfl_xor(acc[e], off);
    }

    __shared__ float lds[4][E_SZ];
    const int wave = t >> 6, lane = t & 63;
    if (lane == 0) {
#pragma unroll
        for (int e = 0; e < E_SZ; ++e) lds[wave][e] = acc[e];
    }
    __syncthreads();

    __shared__ float logits_s[E_SZ];
    if (t < E_SZ) {
        float l = lds[0][t] + lds[1][t] + lds[2][t] + lds[3][t] + bias[t];
        l = (l >= 0.0f) ? l : NEG_SLOPE * l;
        logits_s[t] = l;
    }
    __syncthreads();

    if (t == 0) {
        // top-2 with first-index tie-break (matches jax.lax.top_k)
        int i1 = 0;
        float v1 = logits_s[0];
#pragma unroll
        for (int e = 1; e < E_SZ; ++e) {
            if (logits_s[e] > v1) { v1 = logits_s[e]; i1 = e; }
        }
        int i2 = -1;
        float v2 = -INFINITY;
#pragma unroll
        for (int e = 0; e < E_SZ; ++e) {
            if (e != i1 && logits_s[e] > v2) { v2 = logits_s[e]; i2 = e; }
        }
        // softmax over {v1, v2} (v1 is the max)
        float e2 = expf(v2 - v1);
        float denom = 1.0f + e2;
        float g1 = 1.0f / denom;
        float g2 = e2 / denom;

        float* gating = out + (size_t)b * E_SZ;
        float* mask   = out + (size_t)B_SZ * E_SZ + (size_t)b * E_SZ;
#pragma unroll
        for (int e = 0; e < E_SZ; ++e) { gating[e] = 0.0f; mask[e] = 0.0f; }
        gating[i1] = g1;
        gating[i2] = g2;
        mask[i1]   = 1.0f;
        mask[i2]   = 1.0f;
    }
}

extern "C" void kernel_launch(void* const* d_in, const int* in_sizes, int n_in,
                              void* d_out, int out_size, void* d_ws, size_t ws_size,
                              hipStream_t stream) {
    const float* x    = (const float*)d_in[0];   // [B, D, L]
    const float* W    = (const float*)d_in[1];   // [E, D]
    const float* bias = (const float*)d_in[2];   // [E]
    float* out        = (float*)d_out;           // gating [B,E] ++ mask [B,E]
    float* pooled     = (float*)d_ws;            // [B, D] = 4 MiB scratch

    const int nrows = B_SZ * D_SZ;               // 1M rows
    // 4 waves (rows) per 256-thread block
    const int blocks = (nrows * 64 + 255) / 256;
    pool_kernel<<<blocks, 256, 0, stream>>>(x, pooled, nrows);

    gate_kernel<<<B_SZ, 256, 0, stream>>>(pooled, W, bias, out);
}